// Round 1
// baseline (184.574 us; speedup 1.0000x reference)
//
#include <hip/hip_runtime.h>

// Problem constants (from reference)
#define B_     64
#define NT_    64
#define WIN_   31
#define P_     (WIN_ * WIN_)   // 961
#define H_     512
#define W_     512
#define TW_    40              // tile width: 16B-aligned origin + span 36 -> 40
#define TH_    34              // tile rows
#define TELEMS (TW_ * TH_)     // 1360 floats per frame tile
#define NV_    (TELEMS / 4)    // 340 float4 per frame
#define NCH_   ((NV_ + 63) / 64)  // 6 wave-chunks of 64 float4 per frame

// out: (B, 2, NT, WIN, WIN, 1) float32
// imgs: (B, 2, H, W, 1) float32
// track_locs: (B, NT*2) float32

typedef __attribute__((address_space(1))) const void glob_cv;
typedef __attribute__((address_space(3))) void lds_v;

__global__ __launch_bounds__(256, 8)
void motion_sample_kernel(const float* __restrict__ track_locs,
                          const float* __restrict__ imgs,
                          float* __restrict__ out) {
    // XCD swizzle: b = blk & 63 so all 64 tracks of a batch share blk%8
    // (same XCD under round-robin dispatch) -> L2 reuse of the batch region.
    const int blk = blockIdx.x;          // 0 .. B*NT-1
    const int b = blk & 63;
    const int t = blk >> 6;

    const float scale = (float)WIN_ / (float)W_;       // 31/512
    const float2 tl = *(const float2*)(track_locs + b * (NT_ * 2) + 2 * t);
    const float tx = tl.x;
    const float ty = tl.y;

    const float halfwin = (float)WIN_ * 0.5f;          // 15.5
    const float basex = (-1.0f + tx / scale) * halfwin;
    const float basey = (-1.0f + ty / scale) * halfwin;
    const float step  = (2.0f / (float)(WIN_ - 1)) * halfwin;  // 31/30

    const int xstart = (int)floorf(basex);   // in [-16, 240]
    const int ystart = (int)floorf(basey);
    const int xal    = xstart & ~3;          // 16B-aligned tile origin (floor for negatives)

    __shared__ float tile0[TELEMS];
    __shared__ float tile1[TELEMS];

    const float* frame0 = imgs + (size_t)(b * 2 + 0) * (H_ * W_);
    const float* frame1 = imgs + (size_t)(b * 2 + 1) * (H_ * W_);

    const int tid  = threadIdx.y * 32 + threadIdx.x;
    const int wave = tid >> 6;        // 0..3
    const int lane = tid & 63;

    // Right/bottom never clip (xal <= 240, ystart+TH_-1 <= 273 < 512).
    // Row clamp (ystart < 0) is handled per-lane in the async path, so only
    // left-column clipping (xal < 0, ~6% of blocks) needs the scalar path.
    if (xal >= 0) {
        // Async direct-to-LDS staging: per-lane GLOBAL address, wave-uniform
        // LDS chunk base; HW writes lane l at base + l*16 (linear packed tile).
        // 2 frames x 6 chunks = 12 issues, 3 per wave, one drain at the barrier.
        for (int cw = wave; cw < 2 * NCH_; cw += 4) {
            const int fsel  = cw & 1;
            const int chunk = cw >> 1;
            const int i4 = chunk * 64 + lane;     // float4 index within frame tile
            if (i4 < NV_) {
                const int r  = i4 / 10;           // tile row   (TW_/4 == 10)
                const int c4 = i4 - r * 10;       // float4 col within row
                const int gy = max(ystart + r, 0);  // top clamp only
                const float* gsrc = (fsel ? frame1 : frame0) + gy * W_ + xal + c4 * 4;
                float* ldst = (fsel ? tile1 : tile0) + chunk * 256;  // 1024B chunk base
                __builtin_amdgcn_global_load_lds((glob_cv*)gsrc, (lds_v*)ldst, 16, 0, 0);
            }
        }
    } else {
        // Scalar clamped staging (block-uniform branch; ~6% of blocks).
        for (int idx = tid; idx < TELEMS; idx += 256) {
            const int r = idx / TW_;
            const int c = idx - r * TW_;
            const int gy = min(max(ystart + r, 0), H_ - 1);
            const int gx = min(max(xal + c, 0), W_ - 1);
            const int g = gy * W_ + gx;
            tile0[idx] = frame0[g];
            tile1[idx] = frame1[g];
        }
    }
    __syncthreads();

    float* out0 = out + (size_t)((b * 2 + 0) * NT_ + t) * P_;
    float* out1 = out + (size_t)((b * 2 + 1) * NT_ + t) * P_;

    // lane = column j (0..30); lane 31 idle in compute
    const int j = threadIdx.x;
    if (j < WIN_) {
        // per-lane (column) quantities — computed once
        const float x  = basex + (float)j * step;
        const float fx = floorf(x);
        const float x0f = fminf(fmaxf(fx,        0.0f), (float)(W_ - 1));
        const float x1f = fminf(fmaxf(fx + 1.0f, 0.0f), (float)(W_ - 1));
        const float ax0 = x1f - x;
        const float ax1 = x - x0f;
        const int lx0 = (int)x0f - xal;
        const int lx1 = (int)x1f - xal;

        for (int i = threadIdx.y; i < WIN_; i += 8) {
            const float y  = basey + (float)i * step;
            const float fy = floorf(y);
            const float y0f = fminf(fmaxf(fy,        0.0f), (float)(H_ - 1));
            const float y1f = fminf(fmaxf(fy + 1.0f, 0.0f), (float)(H_ - 1));
            const float ay0 = y1f - y;
            const float ay1 = y - y0f;
            const int r0b = ((int)y0f - ystart) * TW_;
            const int r1b = ((int)y1f - ystart) * TW_;

            const float t0a = tile0[r0b + lx0];
            const float t0b = tile0[r0b + lx1];
            const float t0c = tile0[r1b + lx0];
            const float t0d = tile0[r1b + lx1];
            const float t1a = tile1[r0b + lx0];
            const float t1b = tile1[r0b + lx1];
            const float t1c = tile1[r1b + lx0];
            const float t1d = tile1[r1b + lx1];

            const float r0 = ay0 * (ax0 * t0a + ax1 * t0b) + ay1 * (ax0 * t0c + ax1 * t0d);
            const float r1 = ay0 * (ax0 * t1a + ax1 * t1b) + ay1 * (ax0 * t1c + ax1 * t1d);

            const int p = i * WIN_ + j;
            __builtin_nontemporal_store(r0, &out0[p]);
            __builtin_nontemporal_store(r1, &out1[p]);
        }
    }
}

extern "C" void kernel_launch(void* const* d_in, const int* in_sizes, int n_in,
                              void* d_out, int out_size, void* d_ws, size_t ws_size,
                              hipStream_t stream) {
    const float* track_locs = (const float*)d_in[0];   // (64, 128)
    const float* imgs       = (const float*)d_in[1];   // (64, 2, 512, 512, 1)
    float* out              = (float*)d_out;           // (64, 2, 64, 31, 31, 1)

    const int nblocks = B_ * NT_;   // 4096
    dim3 block(32, 8);
    motion_sample_kernel<<<nblocks, block, 0, stream>>>(track_locs, imgs, out);
}